// Round 1
// baseline (410.855 us; speedup 1.0000x reference)
//
#include <hip/hip_runtime.h>

#define KK 8
#define DD 16
#define NN 32
#define TT 200
#define BB 2048

// per-k LDS slab strides, all == 4 (mod 32) floats so the <=8 distinct
// per-lane k values spread across all 32 banks -> conflict-free ds_read_b128
#define SC 516   // C slab stride (512 used)
#define SA 260   // A slab stride (256 used)
#define SE 36    // emission table stride (32 used)
#define SD 20    // dyn/init table stride (16 used)

__device__ __forceinline__ float dot16(const float* __restrict__ row,
                                       const float* __restrict__ z) {
  const float4* r4 = reinterpret_cast<const float4*>(row);
  float4 c0 = r4[0], c1 = r4[1], c2 = r4[2], c3 = r4[3];
  float a = c0.x * z[0], b = c0.y * z[1];
  a = fmaf(c0.z, z[2], a);  b = fmaf(c0.w, z[3], b);
  a = fmaf(c1.x, z[4], a);  b = fmaf(c1.y, z[5], b);
  a = fmaf(c1.z, z[6], a);  b = fmaf(c1.w, z[7], b);
  a = fmaf(c2.x, z[8], a);  b = fmaf(c2.y, z[9], b);
  a = fmaf(c2.z, z[10], a); b = fmaf(c2.w, z[11], b);
  a = fmaf(c3.x, z[12], a); b = fmaf(c3.y, z[13], b);
  a = fmaf(c3.z, z[14], a); b = fmaf(c3.w, z[15], b);
  return a + b;
}

__global__ __launch_bounds__(256) void slds_lp_kernel(
    const int* __restrict__ dsts,      // [B,T]
    const float* __restrict__ zg,      // [B,T,D]
    const float* __restrict__ obsg,    // [B,T,N]
    const float* __restrict__ initlg,  // [K]
    const float* __restrict__ initloc, // [K,D]
    const float* __restrict__ initls,  // [K,D]
    const float* __restrict__ transg,  // [K,K]
    const float* __restrict__ Ag,      // [K,D,D]
    const float* __restrict__ dynoff,  // [K,D]
    const float* __restrict__ dynls,   // [K,D] (used directly as scale!)
    const float* __restrict__ Cg,      // [K,N,D]
    const float* __restrict__ emoff,   // [K,N]
    const float* __restrict__ emls,    // [K,N]
    float* __restrict__ out)           // [B]
{
  __shared__ __align__(16) float sC[KK * SC];
  __shared__ __align__(16) float sA[KK * SA];
  __shared__ __align__(16) float sEmOff[KK * SE];
  __shared__ __align__(16) float sEmInv[KK * SE];
  __shared__ __align__(16) float sDynOff[KK * SD];
  __shared__ __align__(16) float sDynInv[KK * SD];
  __shared__ __align__(16) float sInitLoc[KK * SD];
  __shared__ __align__(16) float sInitInv[KK * SD];
  __shared__ float sTrans[KK * KK];
  __shared__ float sEmConst[KK];
  __shared__ float sDynConst[KK];
  __shared__ float sInitLp[KK];

  const float HALF_LOG2PI = 0.91893853320467274178f;
  const int tid = threadIdx.x;

  // ---- stage params into LDS (transforms applied once) ----
  for (int i = tid; i < KK * NN * DD; i += 256) {   // 4096
    int k = i >> 9, r = i & 511;
    sC[k * SC + r] = Cg[i];
  }
  for (int i = tid; i < KK * DD * DD; i += 256) {   // 2048
    int k = i >> 8, r = i & 255;
    sA[k * SA + r] = Ag[i];
  }
  if (tid < KK * NN) {                              // 256
    int k = tid >> 5, n = tid & 31;
    sEmOff[k * SE + n] = emoff[tid];
    sEmInv[k * SE + n] = expf(-emls[tid]);
  }
  if (tid < KK * DD) {                              // 128
    int k = tid >> 4, d = tid & 15;
    sDynOff[k * SD + d] = dynoff[tid];
    sDynInv[k * SD + d] = 1.0f / dynls[tid];
    sInitLoc[k * SD + d] = initloc[tid];
    sInitInv[k * SD + d] = expf(-initls[tid]);
  }
  if (tid < KK * KK) {                              // 64: transition log-softmax
    int kr = tid >> 3;
    float mx = transg[kr * KK];
    for (int j = 1; j < KK; ++j) mx = fmaxf(mx, transg[kr * KK + j]);
    float ss = 0.f;
    for (int j = 0; j < KK; ++j) ss += expf(transg[kr * KK + j] - mx);
    sTrans[tid] = transg[tid] - (logf(ss) + mx);
  }
  if (tid < KK) {                                   // per-k constants
    int k = tid;
    float se = 0.f;
    for (int n = 0; n < NN; ++n) se -= emls[k * NN + n];
    sEmConst[k] = se - NN * HALF_LOG2PI;
    float sd = 0.f;
    for (int d = 0; d < DD; ++d) sd -= logf(dynls[k * DD + d]);
    sDynConst[k] = sd - DD * HALF_LOG2PI;
    float mx = initlg[0];
    for (int j = 1; j < KK; ++j) mx = fmaxf(mx, initlg[j]);
    float ss = 0.f;
    for (int j = 0; j < KK; ++j) ss += expf(initlg[j] - mx);
    float si = 0.f;
    for (int d = 0; d < DD; ++d) si -= initls[k * DD + d];
    sInitLp[k] = initlg[k] - (logf(ss) + mx) + si - DD * HALF_LOG2PI;
  }
  __syncthreads();

  // ---- one thread per (b,t) item ----
  const int nItems = BB * TT;
  const int gstride = gridDim.x * blockDim.x;
  for (int item = blockIdx.x * blockDim.x + tid; item < nItems; item += gstride) {
    const int b = item / TT;
    const int t = item - b * TT;

    float z[16];
    {
      const float4* p = reinterpret_cast<const float4*>(zg + (size_t)item * DD);
      float4 a0 = p[0], a1 = p[1], a2 = p[2], a3 = p[3];
      z[0] = a0.x; z[1] = a0.y; z[2] = a0.z; z[3] = a0.w;
      z[4] = a1.x; z[5] = a1.y; z[6] = a1.z; z[7] = a1.w;
      z[8] = a2.x; z[9] = a2.y; z[10] = a2.z; z[11] = a2.w;
      z[12] = a3.x; z[13] = a3.y; z[14] = a3.z; z[15] = a3.w;
    }
    const int s = dsts[item];

    // emissions
    const float4* o4 = reinterpret_cast<const float4*>(obsg + (size_t)item * NN);
    const int cb = s * SC;
    const int eb4 = s * (SE / 4);
    float acc = 0.f;
#pragma unroll
    for (int g = 0; g < 8; ++g) {
      float4 o = o4[g];
      float4 off = reinterpret_cast<const float4*>(sEmOff)[eb4 + g];
      float4 inv = reinterpret_cast<const float4*>(sEmInv)[eb4 + g];
      int n0 = g * 4;
      float l0 = dot16(&sC[cb + (n0 + 0) * DD], z) + off.x;
      float l1 = dot16(&sC[cb + (n0 + 1) * DD], z) + off.y;
      float l2 = dot16(&sC[cb + (n0 + 2) * DD], z) + off.z;
      float l3 = dot16(&sC[cb + (n0 + 3) * DD], z) + off.w;
      float d0 = (o.x - l0) * inv.x;
      float d1 = (o.y - l1) * inv.y;
      float d2 = (o.z - l2) * inv.z;
      float d3 = (o.w - l3) * inv.w;
      acc = fmaf(d0, d0, acc); acc = fmaf(d1, d1, acc);
      acc = fmaf(d2, d2, acc); acc = fmaf(d3, d3, acc);
    }
    float lp = -0.5f * acc + sEmConst[s];

    if (t != 0) {
      const int sp = dsts[item - 1];
      float zp[16];
      {
        const float4* p = reinterpret_cast<const float4*>(zg + (size_t)(item - 1) * DD);
        float4 a0 = p[0], a1 = p[1], a2 = p[2], a3 = p[3];
        zp[0] = a0.x; zp[1] = a0.y; zp[2] = a0.z; zp[3] = a0.w;
        zp[4] = a1.x; zp[5] = a1.y; zp[6] = a1.z; zp[7] = a1.w;
        zp[8] = a2.x; zp[9] = a2.y; zp[10] = a2.z; zp[11] = a2.w;
        zp[12] = a3.x; zp[13] = a3.y; zp[14] = a3.z; zp[15] = a3.w;
      }
      const int ab = s * SA;
      const int db4 = s * (SD / 4);
      float a2acc = 0.f;
#pragma unroll
      for (int g = 0; g < 4; ++g) {
        float4 off = reinterpret_cast<const float4*>(sDynOff)[db4 + g];
        float4 inv = reinterpret_cast<const float4*>(sDynInv)[db4 + g];
        int i0 = g * 4;
        float l0 = dot16(&sA[ab + (i0 + 0) * DD], zp) + off.x;
        float l1 = dot16(&sA[ab + (i0 + 1) * DD], zp) + off.y;
        float l2 = dot16(&sA[ab + (i0 + 2) * DD], zp) + off.z;
        float l3 = dot16(&sA[ab + (i0 + 3) * DD], zp) + off.w;
        float d0 = (z[i0 + 0] - l0) * inv.x;
        float d1 = (z[i0 + 1] - l1) * inv.y;
        float d2 = (z[i0 + 2] - l2) * inv.z;
        float d3 = (z[i0 + 3] - l3) * inv.w;
        a2acc = fmaf(d0, d0, a2acc); a2acc = fmaf(d1, d1, a2acc);
        a2acc = fmaf(d2, d2, a2acc); a2acc = fmaf(d3, d3, a2acc);
      }
      lp += -0.5f * a2acc + sDynConst[s] + sTrans[sp * KK + s];
    } else {
      const int ib4 = s * (SD / 4);
      float a2acc = 0.f;
#pragma unroll
      for (int g = 0; g < 4; ++g) {
        float4 loc = reinterpret_cast<const float4*>(sInitLoc)[ib4 + g];
        float4 inv = reinterpret_cast<const float4*>(sInitInv)[ib4 + g];
        int i0 = g * 4;
        float d0 = (z[i0 + 0] - loc.x) * inv.x;
        float d1 = (z[i0 + 1] - loc.y) * inv.y;
        float d2 = (z[i0 + 2] - loc.z) * inv.z;
        float d3 = (z[i0 + 3] - loc.w) * inv.w;
        a2acc = fmaf(d0, d0, a2acc); a2acc = fmaf(d1, d1, a2acc);
        a2acc = fmaf(d2, d2, a2acc); a2acc = fmaf(d3, d3, a2acc);
      }
      lp += -0.5f * a2acc + sInitLp[s];
    }

    // ---- wave-level segmented sum keyed by b (<=2 segments/wave), then atomic ----
    const int lane = tid & 63;
    float v = lp;
#pragma unroll
    for (int off = 1; off < 64; off <<= 1) {
      float ov = __shfl_up(v, off, 64);
      int obk = __shfl_up(b, off, 64);
      if (lane >= off && obk == b) v += ov;
    }
    int nb = __shfl_down(b, 1, 64);
    if (lane == 63 || nb != b) atomicAdd(&out[b], v);
  }
}

extern "C" void kernel_launch(void* const* d_in, const int* in_sizes, int n_in,
                              void* d_out, int out_size, void* d_ws, size_t ws_size,
                              hipStream_t stream) {
  const int*   dsts    = (const int*)d_in[0];
  const float* zg      = (const float*)d_in[1];
  const float* obsg    = (const float*)d_in[2];
  const float* initlg  = (const float*)d_in[3];
  const float* initloc = (const float*)d_in[4];
  const float* initls  = (const float*)d_in[5];
  const float* transg  = (const float*)d_in[6];
  const float* Ag      = (const float*)d_in[7];
  const float* dynoff  = (const float*)d_in[8];
  const float* dynls   = (const float*)d_in[9];
  const float* Cg      = (const float*)d_in[10];
  const float* emoff   = (const float*)d_in[11];
  const float* emls    = (const float*)d_in[12];
  float* out = (float*)d_out;

  hipMemsetAsync(d_out, 0, BB * sizeof(float), stream);

  // 1600 blocks x 256 threads == exactly B*T items, one per thread
  slds_lp_kernel<<<1600, 256, 0, stream>>>(dsts, zg, obsg, initlg, initloc,
                                           initls, transg, Ag, dynoff, dynls,
                                           Cg, emoff, emls, out);
}

// Round 3
// 143.135 us; speedup vs baseline: 2.8704x; 2.8704x over previous
//
#include <hip/hip_runtime.h>

#define KK 8
#define DD 16
#define NN 32
#define TT 200
#define BB 2048

// per-k LDS slab strides, all == 4 (mod 32) floats so the <=8 distinct
// per-lane k values spread across all 32 banks -> conflict-free ds_read_b128
#define SC 516   // C slab stride (512 used)
#define SA 260   // A slab stride (256 used)
#define SE 36    // emission table stride (32 used)
#define SD 20    // dyn/init table stride (16 used)

__device__ __forceinline__ float dot16(const float* __restrict__ row,
                                       const float* __restrict__ z) {
  const float4* r4 = reinterpret_cast<const float4*>(row);
  float4 c0 = r4[0], c1 = r4[1], c2 = r4[2], c3 = r4[3];
  float a = c0.x * z[0], b = c0.y * z[1];
  a = fmaf(c0.z, z[2], a);  b = fmaf(c0.w, z[3], b);
  a = fmaf(c1.x, z[4], a);  b = fmaf(c1.y, z[5], b);
  a = fmaf(c1.z, z[6], a);  b = fmaf(c1.w, z[7], b);
  a = fmaf(c2.x, z[8], a);  b = fmaf(c2.y, z[9], b);
  a = fmaf(c2.z, z[10], a); b = fmaf(c2.w, z[11], b);
  a = fmaf(c3.x, z[12], a); b = fmaf(c3.y, z[13], b);
  a = fmaf(c3.z, z[14], a); b = fmaf(c3.w, z[15], b);
  return a + b;
}

// NOTE: no min-waves clause. Round 2's __launch_bounds__(256,4) (forced
// <=128 VGPR -> guaranteed scratch spill) core-dumped under graph capture.
// Register pressure is instead controlled by "#pragma unroll 2" below
// (Round 1's full unroll hit 256 VGPR + ~700 MB spill traffic).
__global__ __launch_bounds__(256) void slds_lp_kernel(
    const int* __restrict__ dsts,      // [B,T]
    const float* __restrict__ zg,      // [B,T,D]
    const float* __restrict__ obsg,    // [B,T,N]
    const float* __restrict__ initlg,  // [K]
    const float* __restrict__ initloc, // [K,D]
    const float* __restrict__ initls,  // [K,D]
    const float* __restrict__ transg,  // [K,K]
    const float* __restrict__ Ag,      // [K,D,D]
    const float* __restrict__ dynoff,  // [K,D]
    const float* __restrict__ dynls,   // [K,D] (scale directly, NOT log)
    const float* __restrict__ Cg,      // [K,N,D]
    const float* __restrict__ emoff,   // [K,N]
    const float* __restrict__ emls,    // [K,N]
    float* __restrict__ out)           // [B]
{
  __shared__ __align__(16) float sC[KK * SC];
  __shared__ __align__(16) float sA[KK * SA];
  __shared__ __align__(16) float sEmOff[KK * SE];
  __shared__ __align__(16) float sEmInv[KK * SE];
  __shared__ __align__(16) float sDynOff[KK * SD];
  __shared__ __align__(16) float sDynInv[KK * SD];
  __shared__ __align__(16) float sInitLoc[KK * SD];
  __shared__ __align__(16) float sInitInv[KK * SD];
  __shared__ float sTrans[KK * KK];
  __shared__ float sEmConst[KK];
  __shared__ float sDynConst[KK];
  __shared__ float sInitLp[KK];

  const float HALF_LOG2PI = 0.91893853320467274178f;
  const int tid = threadIdx.x;

  // ---- stage params into LDS (transforms applied once per block) ----
  for (int i = tid; i < KK * NN * DD; i += 256) {   // 4096
    int k = i >> 9, r = i & 511;
    sC[k * SC + r] = Cg[i];
  }
  for (int i = tid; i < KK * DD * DD; i += 256) {   // 2048
    int k = i >> 8, r = i & 255;
    sA[k * SA + r] = Ag[i];
  }
  if (tid < KK * NN) {                              // 256
    int k = tid >> 5, n = tid & 31;
    sEmOff[k * SE + n] = emoff[tid];
    sEmInv[k * SE + n] = expf(-emls[tid]);
  }
  if (tid < KK * DD) {                              // 128
    int k = tid >> 4, d = tid & 15;
    sDynOff[k * SD + d] = dynoff[tid];
    sDynInv[k * SD + d] = 1.0f / dynls[tid];
    sInitLoc[k * SD + d] = initloc[tid];
    sInitInv[k * SD + d] = expf(-initls[tid]);
  }
  if (tid < KK * KK) {                              // 64: transition log-softmax
    int kr = tid >> 3;
    float mx = transg[kr * KK];
    for (int j = 1; j < KK; ++j) mx = fmaxf(mx, transg[kr * KK + j]);
    float ss = 0.f;
    for (int j = 0; j < KK; ++j) ss += expf(transg[kr * KK + j] - mx);
    sTrans[tid] = transg[tid] - (logf(ss) + mx);
  }
  if (tid < KK) {                                   // per-k constants
    int k = tid;
    float se = 0.f;
    for (int n = 0; n < NN; ++n) se -= emls[k * NN + n];
    sEmConst[k] = se - NN * HALF_LOG2PI;
    float sd = 0.f;
    for (int d = 0; d < DD; ++d) sd -= logf(dynls[k * DD + d]);
    sDynConst[k] = sd - DD * HALF_LOG2PI;
    float mx = initlg[0];
    for (int j = 1; j < KK; ++j) mx = fmaxf(mx, initlg[j]);
    float ss = 0.f;
    for (int j = 0; j < KK; ++j) ss += expf(initlg[j] - mx);
    float si = 0.f;
    for (int d = 0; d < DD; ++d) si -= initls[k * DD + d];
    sInitLp[k] = initlg[k] - (logf(ss) + mx) + si - DD * HALF_LOG2PI;
  }
  __syncthreads();

  // ---- one thread per (b,t) item ----
  const int nItems = BB * TT;
  const int gstride = gridDim.x * blockDim.x;
  for (int item = blockIdx.x * blockDim.x + tid; item < nItems; item += gstride) {
    const int b = item / TT;
    const int t = item - b * TT;

    float z[16];
    {
      const float4* p = reinterpret_cast<const float4*>(zg + (size_t)item * DD);
      float4 a0 = p[0], a1 = p[1], a2 = p[2], a3 = p[3];
      z[0] = a0.x; z[1] = a0.y; z[2] = a0.z; z[3] = a0.w;
      z[4] = a1.x; z[5] = a1.y; z[6] = a1.z; z[7] = a1.w;
      z[8] = a2.x; z[9] = a2.y; z[10] = a2.z; z[11] = a2.w;
      z[12] = a3.x; z[13] = a3.y; z[14] = a3.z; z[15] = a3.w;
    }
    const int s = dsts[item];

    // emissions -- unroll 2 keeps ~2 rows of LDS data live (reg pressure)
    const float4* o4 = reinterpret_cast<const float4*>(obsg + (size_t)item * NN);
    const int cb = s * SC;
    const int eb4 = s * (SE / 4);
    float acc = 0.f;
#pragma unroll 2
    for (int g = 0; g < 8; ++g) {
      float4 o = o4[g];
      float4 off = reinterpret_cast<const float4*>(sEmOff)[eb4 + g];
      float4 inv = reinterpret_cast<const float4*>(sEmInv)[eb4 + g];
      int n0 = g * 4;
      float l0 = dot16(&sC[cb + (n0 + 0) * DD], z) + off.x;
      float l1 = dot16(&sC[cb + (n0 + 1) * DD], z) + off.y;
      float l2 = dot16(&sC[cb + (n0 + 2) * DD], z) + off.z;
      float l3 = dot16(&sC[cb + (n0 + 3) * DD], z) + off.w;
      float d0 = (o.x - l0) * inv.x;
      float d1 = (o.y - l1) * inv.y;
      float d2 = (o.z - l2) * inv.z;
      float d3 = (o.w - l3) * inv.w;
      acc = fmaf(d0, d0, acc); acc = fmaf(d1, d1, acc);
      acc = fmaf(d2, d2, acc); acc = fmaf(d3, d3, acc);
    }
    float lp = -0.5f * acc + sEmConst[s];

    if (t != 0) {
      const int sp = dsts[item - 1];
      float zp[16];
      {
        const float4* p = reinterpret_cast<const float4*>(zg + (size_t)(item - 1) * DD);
        float4 a0 = p[0], a1 = p[1], a2 = p[2], a3 = p[3];
        zp[0] = a0.x; zp[1] = a0.y; zp[2] = a0.z; zp[3] = a0.w;
        zp[4] = a1.x; zp[5] = a1.y; zp[6] = a1.z; zp[7] = a1.w;
        zp[8] = a2.x; zp[9] = a2.y; zp[10] = a2.z; zp[11] = a2.w;
        zp[12] = a3.x; zp[13] = a3.y; zp[14] = a3.z; zp[15] = a3.w;
      }
      const int ab = s * SA;
      const int db4 = s * (SD / 4);
      float a2acc = 0.f;
#pragma unroll 2
      for (int g = 0; g < 4; ++g) {
        float4 off = reinterpret_cast<const float4*>(sDynOff)[db4 + g];
        float4 inv = reinterpret_cast<const float4*>(sDynInv)[db4 + g];
        int i0 = g * 4;
        float l0 = dot16(&sA[ab + (i0 + 0) * DD], zp) + off.x;
        float l1 = dot16(&sA[ab + (i0 + 1) * DD], zp) + off.y;
        float l2 = dot16(&sA[ab + (i0 + 2) * DD], zp) + off.z;
        float l3 = dot16(&sA[ab + (i0 + 3) * DD], zp) + off.w;
        float d0 = (z[i0 + 0] - l0) * inv.x;
        float d1 = (z[i0 + 1] - l1) * inv.y;
        float d2 = (z[i0 + 2] - l2) * inv.z;
        float d3 = (z[i0 + 3] - l3) * inv.w;
        a2acc = fmaf(d0, d0, a2acc); a2acc = fmaf(d1, d1, a2acc);
        a2acc = fmaf(d2, d2, a2acc); a2acc = fmaf(d3, d3, a2acc);
      }
      lp += -0.5f * a2acc + sDynConst[s] + sTrans[sp * KK + s];
    } else {
      const int ib4 = s * (SD / 4);
      float a2acc = 0.f;
#pragma unroll 2
      for (int g = 0; g < 4; ++g) {
        float4 loc = reinterpret_cast<const float4*>(sInitLoc)[ib4 + g];
        float4 inv = reinterpret_cast<const float4*>(sInitInv)[ib4 + g];
        int i0 = g * 4;
        float d0 = (z[i0 + 0] - loc.x) * inv.x;
        float d1 = (z[i0 + 1] - loc.y) * inv.y;
        float d2 = (z[i0 + 2] - loc.z) * inv.z;
        float d3 = (z[i0 + 3] - loc.w) * inv.w;
        a2acc = fmaf(d0, d0, a2acc); a2acc = fmaf(d1, d1, a2acc);
        a2acc = fmaf(d2, d2, a2acc); a2acc = fmaf(d3, d3, a2acc);
      }
      lp += -0.5f * a2acc + sInitLp[s];
    }

    // ---- wave-level segmented sum keyed by b (<=2 segments/wave), then atomic ----
    const int lane = tid & 63;
    float v = lp;
#pragma unroll
    for (int off = 1; off < 64; off <<= 1) {
      float ov = __shfl_up(v, off, 64);
      int obk = __shfl_up(b, off, 64);
      if (lane >= off && obk == b) v += ov;
    }
    int nb = __shfl_down(b, 1, 64);
    if (lane == 63 || nb != b) atomicAdd(&out[b], v);
  }
}

extern "C" void kernel_launch(void* const* d_in, const int* in_sizes, int n_in,
                              void* d_out, int out_size, void* d_ws, size_t ws_size,
                              hipStream_t stream) {
  const int*   dsts    = (const int*)d_in[0];
  const float* zg      = (const float*)d_in[1];
  const float* obsg    = (const float*)d_in[2];
  const float* initlg  = (const float*)d_in[3];
  const float* initloc = (const float*)d_in[4];
  const float* initls  = (const float*)d_in[5];
  const float* transg  = (const float*)d_in[6];
  const float* Ag      = (const float*)d_in[7];
  const float* dynoff  = (const float*)d_in[8];
  const float* dynls   = (const float*)d_in[9];
  const float* Cg      = (const float*)d_in[10];
  const float* emoff   = (const float*)d_in[11];
  const float* emls    = (const float*)d_in[12];
  float* out = (float*)d_out;

  hipMemsetAsync(d_out, 0, BB * sizeof(float), stream);

  // 1600 blocks x 256 threads == exactly B*T items, one per thread
  slds_lp_kernel<<<1600, 256, 0, stream>>>(dsts, zg, obsg, initlg, initloc,
                                           initls, transg, Ag, dynoff, dynls,
                                           Cg, emoff, emls, out);
}